// Round 9
// baseline (82.725 us; speedup 1.0000x reference)
//
#include <hip/hip_runtime.h>

#define EPS 1e-5f
#define TEMP 50.0f
#define CCH 64
#define HH 128
#define WW 128
#define HWSZ (HH * WW)
#define CEPS2 (CCH * EPS * EPS)

#define ITW 8           // interior tile: 8 wide
#define ITH 4           // x 4 high = 32 px/block
#define HTW 12          // halo: 12 wide
#define HTH 8           //       8 high
#define HPX (HTW * HTH) // 96 halo pixels
#define HPAD 97         // HPAD%4==1: quarter-plane stride 2*HPAD*4 words == 8
                        // mod 32 -> 8-lane group (2px x 4 quarters) covers all
                        // 32 banks: conflict-free b128

typedef _Float16 h16;
typedef h16 h2v __attribute__((ext_vector_type(2)));
typedef h16 h8v __attribute__((ext_vector_type(8)));
union H8 { h8v v; h2v p[4]; };

__device__ __forceinline__ float fdot2(h2v a, h2v b, float c) {
#if __has_builtin(__builtin_amdgcn_fdot2)
    return __builtin_amdgcn_fdot2(a, b, c, false);   // v_dot2_f32_f16
#else
    return c + (float)a[0] * (float)b[0] + (float)a[1] * (float)b[1];
#endif
}

// Quad-lane butterfly sum via DPP quad_perm (VALU pipe, no LDS traffic).
__device__ __forceinline__ float quad_sum(float x) {
#if __has_builtin(__builtin_amdgcn_mov_dpp)
    int i = __builtin_bit_cast(int, x);
    int a = __builtin_amdgcn_mov_dpp(i, 0xB1, 0xF, 0xF, true);  // xor 1
    float x1 = x + __builtin_bit_cast(float, a);
    int j = __builtin_bit_cast(int, x1);
    int b = __builtin_amdgcn_mov_dpp(j, 0x4E, 0xF, 0xF, true);  // xor 2
    return x1 + __builtin_bit_cast(float, b);
#else
    float x1 = x + __shfl_xor(x, 1);
    return x1 + __shfl_xor(x1, 2);
#endif
}

// ---- Kernel A: [B][C][H][W] f32 -> [B][H][W][C] f16 (channel-last) ----
#define TP_PAD 72       // h16 row stride: 144 B, 16B-aligned
__global__ __launch_bounds__(256) void rv_transpose(const float* __restrict__ x,
                                                    h16* __restrict__ xt) {
    __shared__ h16 buf[WW][TP_PAD];          // 18432 B
    const int t = threadIdx.x;
    const int h = blockIdx.x;
    const int b = blockIdx.y;
    const float* src = x + (size_t)b * (CCH * HWSZ) + h * WW;
#pragma unroll 8
    for (int i = 0; i < 32; ++i) {           // 64 ch x 128 w / 256 threads
        int k = i * 256 + t;
        int c = k >> 7;                      // coalesced: w fast across lanes
        int w = k & 127;
        buf[w][c] = (h16)src[(size_t)c * HWSZ + w];
    }
    __syncthreads();
    h16* dst = xt + (size_t)(b * HH + h) * WW * CCH;
#pragma unroll
    for (int j = 0; j < 4; ++j) {            // 128 px x 8 quads / 256 threads
        int idx = j * 256 + t;
        int w = idx >> 3;
        int q = idx & 7;                     // q fast: contiguous b128 stores
        h8v v = *(const h8v*)&buf[w][q * 8];
        *(h8v*)&dst[(size_t)w * CCH + q * 8] = v;
    }
}

// ---- Kernel B: fused one-pass (center logit == softmax max, exactly) ----
// Block: 128 threads = 2 waves, 8x4 interior tile. thread t -> pixel (t>>2),
// channel-quarter (t&3). Quarter-dot reduction = DPP quad butterfly.
__global__ __launch_bounds__(128, 4) void rv_fused(const h16* __restrict__ xt,
                                                   float* __restrict__ out) {
    __shared__ h8v  tile[8][HPAD];   // 12416 B
    __shared__ float sh_q[HPX];      // 384 B

    const int t  = threadIdx.x;
    const int w0 = blockIdx.x * ITW;
    const int h0 = blockIdx.y * ITH;
    const int b  = blockIdx.z;

    // ---- Stage: 96 px x 8 quads = 768 h8v, 6 iters. 8-lane group = one
    // pixel's 128 B contiguous global read; conflict-free b128 LDS write. ----
#pragma unroll
    for (int it = 0; it < 6; ++it) {
        int k = it * 128 + t;            // 0..767
        int q  = k & 7;
        int px = k >> 3;                 // 0..95
        int row = px / HTW;
        int col = px - row * HTW;
        int gh = h0 + row - 2;
        int gw = w0 + col - 2;
        h8v v = {};
        if (gh >= 0 && gh < HH && gw >= 0 && gw < WW) {
            v = *(const h8v*)&xt[((size_t)(b * HH + gh) * WW + gw) * CCH + q * 8];
        }
        tile[q][px] = v;
    }
    __syncthreads();

    // ---- Per-halo-pixel sumsq (from the SAME rounded f16 values) ----
    if (t < HPX) {
        float q = 0.f;
#pragma unroll
        for (int hq = 0; hq < 8; ++hq) {
            H8 u; u.v = tile[hq][t];
#pragma unroll
            for (int j = 0; j < 4; ++j) q = fdot2(u.p[j], u.p[j], q);
        }
        sh_q[t] = q;
    }
    __syncthreads();

    const int qg  = t & 3;               // channel quarter: planes 2qg, 2qg+1
    const int pix = t >> 2;              // 0..31
    const int r   = pix >> 3;            // 0..3
    const int cl  = pix & 7;             // 0..7
    const int cpx = (r + 2) * HTW + (cl + 2);

    const float rinvC = rsqrtf(sh_q[cpx] + CEPS2);

    H8 ctr0, ctr1;
    ctr0.v = tile[2 * qg][cpx];
    ctr1.v = tile[2 * qg + 1][cpx];

    h2v acc[8] = {};                     // unnormalized numerator, 16 ch
    float wsum = 0.f;

#pragma unroll
    for (int dr = 0; dr < 5; ++dr) {
#pragma unroll
        for (int dc = 0; dc < 5; ++dc) {
            const int npx = (r + dr) * HTW + (cl + dc);
            H8 a0, a1;
            a0.v = tile[2 * qg][npx];
            a1.v = tile[2 * qg + 1][npx];
            float d = 0.f;
#pragma unroll
            for (int j = 0; j < 4; ++j) d = fdot2(ctr0.p[j], a0.p[j], d);
#pragma unroll
            for (int j = 0; j < 4; ++j) d = fdot2(ctr1.p[j], a1.p[j], d);
            d = quad_sum(d);             // full 64-ch dot in all 4 quad lanes
            // weight relative to center: exp(TEMP*(sim-1)), sim<=1 exact max
            const float N2n = sh_q[npx] + CEPS2;
            const float sim = (d + CEPS2) * (rsqrtf(N2n) * rinvC);
            const float wn = __expf(fmaf(TEMP, sim, -TEMP));
            wsum += wn;
            const h16 wh = (h16)wn;
            const h2v w2 = {wh, wh};
#pragma unroll
            for (int j = 0; j < 4; ++j) {
                acc[j]     = a0.p[j] * w2 + acc[j];
                acc[4 + j] = a1.p[j] * w2 + acc[4 + j];
            }
        }
    }

    // ---- Normalize + store this quarter's 16 channels ----
    const float rs = 1.f / wsum;
    const size_t obase = (size_t)b * (CCH * HWSZ)
                       + (size_t)(qg * 16) * HWSZ
                       + (h0 + r) * WW + (w0 + cl);
#pragma unroll
    for (int j = 0; j < 8; ++j) {
        const float f0 = (float)acc[j][0];
        const float f1 = (float)acc[j][1];
        out[obase + (size_t)(2 * j) * HWSZ]     = fmaf(f0, rs, EPS);
        out[obase + (size_t)(2 * j + 1) * HWSZ] = fmaf(f1, rs, EPS);
    }
}

extern "C" void kernel_launch(void* const* d_in, const int* in_sizes, int n_in,
                              void* d_out, int out_size, void* d_ws, size_t ws_size,
                              hipStream_t stream) {
    const float* x = (const float*)d_in[0];
    float* outp = (float*)d_out;
    h16* xt = (h16*)d_ws;    // 4*128*128*64*2 B = 8.4 MB

    rv_transpose<<<dim3(HH, 4), dim3(256), 0, stream>>>(x, xt);
    rv_fused<<<dim3(WW / ITW, HH / ITH, 4), dim3(128, 1, 1), 0, stream>>>(xt, outp);
}